// Round 1
// baseline (1909.312 us; speedup 1.0000x reference)
//
#include <hip/hip_runtime.h>
#include <stdint.h>

#define Dm 1024
#define Sm 2048
#define Bm 2
#define Vm 32000
#define NLm 6

typedef __bf16 bf16x8 __attribute__((ext_vector_type(8)));
typedef __bf16 bf16x4 __attribute__((ext_vector_type(4)));
typedef float f32x4 __attribute__((ext_vector_type(4)));

__device__ __forceinline__ void async_cp16(const void* gp, void* lp) {
  __builtin_amdgcn_global_load_lds(
      (__attribute__((address_space(1))) void*)(gp),
      (__attribute__((address_space(3))) void*)(lp), 16, 0, 0);
}

// ---------------- fp32 -> bf16 convert ----------------
__global__ __launch_bounds__(256) void k_cvt_bf16(const float* __restrict__ src,
                                                  __bf16* __restrict__ dst, int n4) {
  int i = blockIdx.x * 256 + threadIdx.x;
  if (i < n4) {
    float4 v = ((const float4*)src)[i];
    bf16x4 o;
    o.x = (__bf16)v.x; o.y = (__bf16)v.y; o.z = (__bf16)v.z; o.w = (__bf16)v.w;
    ((bf16x4*)dst)[i] = o;
  }
}

// ---------------- out_W (K=1024, V=32000) -> Wt (V, K) bf16 ----------------
__global__ __launch_bounds__(256) void k_transpose_cvt(const float* __restrict__ W,
                                                       __bf16* __restrict__ Wt) {
  __shared__ float tile[32 * 33];
  int t = threadIdx.x;
  int v0 = blockIdx.x * 32;
  int k0 = blockIdx.y * 32;
  {
    int kl = t >> 3, vl4 = (t & 7) * 4;
    float4 v = *(const float4*)(W + (size_t)(k0 + kl) * Vm + v0 + vl4);
    tile[kl * 33 + vl4 + 0] = v.x;
    tile[kl * 33 + vl4 + 1] = v.y;
    tile[kl * 33 + vl4 + 2] = v.z;
    tile[kl * 33 + vl4 + 3] = v.w;
  }
  __syncthreads();
  {
    int vl = t >> 3, kl4 = (t & 7) * 4;
    bf16x4 o;
    o.x = (__bf16)tile[(kl4 + 0) * 33 + vl];
    o.y = (__bf16)tile[(kl4 + 1) * 33 + vl];
    o.z = (__bf16)tile[(kl4 + 2) * 33 + vl];
    o.w = (__bf16)tile[(kl4 + 3) * 33 + vl];
    *(bf16x4*)(Wt + (size_t)(v0 + vl) * Dm + k0 + kl4) = o;
  }
}

// ---------------- embedding gather + sinusoid ----------------
__global__ __launch_bounds__(256) void k_embed(const int* __restrict__ ids,
                                               const float* __restrict__ emb,
                                               float* __restrict__ x,
                                               __bf16* __restrict__ xbf) {
  int row = blockIdx.x;          // b*S + s
  int s = row & (Sm - 1);
  int t = threadIdx.x;
  int id = ids[row];
  int d = t * 4;
  float4 e = *(const float4*)(emb + (size_t)id * Dm + d);
  float v[4] = {e.x, e.y, e.z, e.w};
  float o[4];
#pragma unroll
  for (int i = 0; i < 4; i++) {
    int dd = d + i;
    float ip = (float)(dd & ~1);
    float freq = expf(ip * -0.0089944730195079f);  // -ln(10000)/1024
    float ang = (float)s * freq;
    float pe = (dd & 1) ? cosf(ang) : sinf(ang);
    o[i] = v[i] + pe;
  }
  float4 o4 = {o[0], o[1], o[2], o[3]};
  *(float4*)(x + (size_t)row * Dm + d) = o4;
  bf16x4 ob;
  ob.x = (__bf16)o[0]; ob.y = (__bf16)o[1]; ob.z = (__bf16)o[2]; ob.w = (__bf16)o[3];
  *(bf16x4*)(xbf + (size_t)row * Dm + d) = ob;
}

// ---------------- layernorm ----------------
__device__ __forceinline__ float wave_block_sum(float v, float* red) {
#pragma unroll
  for (int o = 32; o > 0; o >>= 1) v += __shfl_xor(v, o, 64);
  int t = threadIdx.x;
  if ((t & 63) == 0) red[t >> 6] = v;
  __syncthreads();
  return red[0] + red[1] + red[2] + red[3];
}

__global__ __launch_bounds__(256) void k_ln_f32(const float* __restrict__ x,
                                                const float* __restrict__ g,
                                                const float* __restrict__ b,
                                                float* __restrict__ out) {
  __shared__ float red1[4], red2[4];
  int row = blockIdx.x, t = threadIdx.x;
  const float* xr = x + (size_t)row * Dm;
  int d = t * 4;
  float4 v = *(const float4*)(xr + d);
  float mean = wave_block_sum(v.x + v.y + v.z + v.w, red1) * (1.0f / Dm);
  float dx = v.x - mean, dy = v.y - mean, dz = v.z - mean, dw = v.w - mean;
  float var = wave_block_sum(dx * dx + dy * dy + dz * dz + dw * dw, red2) * (1.0f / Dm);
  float rstd = rsqrtf(var + 1e-5f);
  float4 gg = *(const float4*)(g + d);
  float4 bb = *(const float4*)(b + d);
  float4 o = {dx * rstd * gg.x + bb.x, dy * rstd * gg.y + bb.y,
              dz * rstd * gg.z + bb.z, dw * rstd * gg.w + bb.w};
  *(float4*)(out + (size_t)row * Dm + d) = o;
}

__global__ __launch_bounds__(256) void k_ln_bf16(const float* __restrict__ x,
                                                 const float* __restrict__ g,
                                                 const float* __restrict__ b,
                                                 __bf16* __restrict__ out) {
  __shared__ float red1[4], red2[4];
  int row = blockIdx.x, t = threadIdx.x;
  const float* xr = x + (size_t)row * Dm;
  int d = t * 4;
  float4 v = *(const float4*)(xr + d);
  float mean = wave_block_sum(v.x + v.y + v.z + v.w, red1) * (1.0f / Dm);
  float dx = v.x - mean, dy = v.y - mean, dz = v.z - mean, dw = v.w - mean;
  float var = wave_block_sum(dx * dx + dy * dy + dz * dz + dw * dw, red2) * (1.0f / Dm);
  float rstd = rsqrtf(var + 1e-5f);
  float4 gg = *(const float4*)(g + d);
  float4 bb = *(const float4*)(b + d);
  bf16x4 o;
  o.x = (__bf16)(dx * rstd * gg.x + bb.x);
  o.y = (__bf16)(dy * rstd * gg.y + bb.y);
  o.z = (__bf16)(dz * rstd * gg.z + bb.z);
  o.w = (__bf16)(dw * rstd * gg.w + bb.w);
  *(bf16x4*)(out + (size_t)row * Dm + d) = o;
}

// ---------------- depthwise conv chain: conv3 -> conv64(+c) -> conv64 -> mix -> silu ----
// tile: 16 channels x 256 outputs, halo 65 left / 63 right. h is (B,S,D) f32.
#define CSTR 385
#define G1STR 388
#define G2STR 324
#define FSTR 68
__global__ __launch_bounds__(256) void k_conv(const float* __restrict__ h,
                                              const float* __restrict__ w3g,
                                              const float* __restrict__ f0g,
                                              const float* __restrict__ f1g,
                                              const float* __restrict__ mixg,
                                              __bf16* __restrict__ ybf) {
  __shared__ __align__(16) float Cb[16 * CSTR];
  __shared__ __align__(16) float G1[16 * G1STR];
  __shared__ __align__(16) float G2[16 * G2STR];
  __shared__ __align__(16) float F0[16 * FSTR];
  __shared__ __align__(16) float F1[16 * FSTR];
  __shared__ float W3[16 * 4];
  __shared__ float MIXW[16];
  int t = threadIdx.x;
  int s0 = blockIdx.x * 256;
  int d0 = blockIdx.y * 16;
  int bb = blockIdx.z;
  const float* hb = h + (size_t)bb * Sm * Dm;

  for (int i = t; i < 1024; i += 256) {
    int dd = i >> 6, j = i & 63;
    F0[dd * FSTR + j] = f0g[(d0 + dd) * 64 + j];
    F1[dd * FSTR + j] = f1g[(d0 + dd) * 64 + j];
  }
  if (t < 48) { int dd = t / 3, j = t - dd * 3; W3[dd * 4 + j] = w3g[(d0 + dd) * 3 + j]; }
  if (t < 16) MIXW[t] = mixg[d0 + t];

  // stage c: s in [s0-65, s0+319)
#pragma unroll
  for (int k = 0; k < 24; k++) {
    int i = t + k * 256;
    int dl = i & 15, si = i >> 4;
    int s = s0 - 65 + si;
    float v = 0.0f;
    if (s >= 0 && s < Sm) v = hb[(size_t)s * Dm + d0 + dl];
    Cb[dl * CSTR + si] = v;
  }
  __syncthreads();

  // g1 = conv3(c), v in [s0-64, s0+318), zero outside [0,S)
#pragma unroll
  for (int k = 0; k < 24; k++) {
    int i = t + k * 256;
    if (i < 6112) {
      int dl = i & 15, vi = i >> 4;
      int v = s0 - 64 + vi;
      float r = 0.0f;
      if (v >= 0 && v < Sm) {
        const float* c = &Cb[dl * CSTR + vi];
        const float* w = &W3[dl * 4];
        r = w[0] * c[0] + w[1] * c[1] + w[2] * c[2];
      }
      G1[dl * G1STR + vi] = r;
    }
  }
  __syncthreads();

  // g2 = conv64(g1, f0) + c, u in [s0-32, s0+287), zero outside [0,S)
#pragma unroll
  for (int k = 0; k < 5; k++) {
    int bo = t + k * 256;           // 0..1279
    int dl = bo & 15;
    int ui0 = (bo >> 4) << 2;       // 0..316 (ui=319 is discarded pad)
    const float* g1r = &G1[dl * G1STR + ui0];
    const float* f0r = &F0[dl * FSTR];
    float a0 = 0.f, a1 = 0.f, a2 = 0.f, a3 = 0.f;
#pragma unroll
    for (int j4 = 0; j4 < 16; j4++) {
      float4 f = *(const float4*)(f0r + j4 * 4);
      float4 wa = *(const float4*)(g1r + j4 * 4);
      float4 wb = *(const float4*)(g1r + j4 * 4 + 4);
      a0 += f.x * wa.x + f.y * wa.y + f.z * wa.z + f.w * wa.w;
      a1 += f.x * wa.y + f.y * wa.z + f.z * wa.w + f.w * wb.x;
      a2 += f.x * wa.z + f.y * wa.w + f.z * wb.x + f.w * wb.y;
      a3 += f.x * wa.w + f.y * wb.x + f.z * wb.y + f.w * wb.z;
    }
    float* g2r = &G2[dl * G2STR];
    float acc[4] = {a0, a1, a2, a3};
#pragma unroll
    for (int r = 0; r < 4; r++) {
      int ui = ui0 + r;
      int u = s0 - 32 + ui;
      float val = acc[r] + Cb[dl * CSTR + ui + 33];
      g2r[ui] = (u >= 0 && u < Sm) ? val : 0.0f;
    }
  }
  __syncthreads();

  // g3 = conv64(g2, f1); y = silu(g3 * mix); write bf16 (B,S,D)
#pragma unroll
  for (int k = 0; k < 4; k++) {
    int bo = t + k * 256;           // 0..1023
    int dl = bo & 15;
    int ti0 = (bo >> 4) << 2;       // 0..252
    const float* g2r = &G2[dl * G2STR + ti0];
    const float* f1r = &F1[dl * FSTR];
    float a0 = 0.f, a1 = 0.f, a2 = 0.f, a3 = 0.f;
#pragma unroll
    for (int j4 = 0; j4 < 16; j4++) {
      float4 f = *(const float4*)(f1r + j4 * 4);
      float4 wa = *(const float4*)(g2r + j4 * 4);
      float4 wb = *(const float4*)(g2r + j4 * 4 + 4);
      a0 += f.x * wa.x + f.y * wa.y + f.z * wa.z + f.w * wa.w;
      a1 += f.x * wa.y + f.y * wa.z + f.z * wa.w + f.w * wb.x;
      a2 += f.x * wa.z + f.y * wa.w + f.z * wb.x + f.w * wb.y;
      a3 += f.x * wa.w + f.y * wb.x + f.z * wb.y + f.w * wb.z;
    }
    float mixv = MIXW[dl];
    float acc[4] = {a0, a1, a2, a3};
#pragma unroll
    for (int r = 0; r < 4; r++) {
      float m = acc[r] * mixv;
      float yv = m / (1.0f + __expf(-m));
      ybf[(size_t)(bb * Sm + s0 + ti0 + r) * Dm + d0 + dl] = (__bf16)yv;
    }
  }
}

// ---------------- fused dual GEMM (refined + gate) with gating epilogue ----------------
// C1 = y @ rW^T, C2 = x @ gW^T ; x_next = sig(C2+gb)*(C1+rb) + (1-sig)*x
__global__ __launch_bounds__(256, 1) void k_dual_gemm(
    const __bf16* __restrict__ Ay, const __bf16* __restrict__ Ax,
    const __bf16* __restrict__ Br, const __bf16* __restrict__ Bg,
    const float* __restrict__ rb, const float* __restrict__ gb,
    const float* __restrict__ xin, float* __restrict__ xout,
    __bf16* __restrict__ xbfout) {
  __shared__ __align__(16) __bf16 sAy[128 * 32];
  __shared__ __align__(16) __bf16 sAx[128 * 32];
  __shared__ __align__(16) __bf16 sBr[128 * 32];
  __shared__ __align__(16) __bf16 sBg[128 * 32];
  int t = threadIdx.x;
  int n0 = blockIdx.x * 128;
  int m0 = blockIdx.y * 128;
  int wave = t >> 6, lane = t & 63;
  int q = lane >> 4, rr = lane & 15;
  int wm = (wave >> 1) * 64, wn = (wave & 1) * 64;
  int srow = t >> 2;
  int scol = (t & 3) * 8;
  unsigned ldsoff = (unsigned)wave * 1024;
  f32x4 zero = {0.f, 0.f, 0.f, 0.f};
  f32x4 accR[4][4], accG[4][4];
#pragma unroll
  for (int i = 0; i < 4; i++)
#pragma unroll
    for (int j = 0; j < 4; j++) { accR[i][j] = zero; accG[i][j] = zero; }

  for (int kk = 0; kk < 1024; kk += 32) {
#pragma unroll
    for (int c = 0; c < 2; c++) {
      size_t ga = (size_t)(m0 + c * 64 + srow) * 1024 + kk + scol;
      size_t gbo = (size_t)(n0 + c * 64 + srow) * 1024 + kk + scol;
      unsigned lo = c * 4096 + ldsoff;
      async_cp16(Ay + ga, (char*)sAy + lo);
      async_cp16(Ax + ga, (char*)sAx + lo);
      async_cp16(Br + gbo, (char*)sBr + lo);
      async_cp16(Bg + gbo, (char*)sBg + lo);
    }
    __syncthreads();
    bf16x8 fay[4], fax[4], fbr[4], fbg[4];
#pragma unroll
    for (int i = 0; i < 4; i++) {
      int ro = (wm + i * 16 + rr) * 32 + q * 8;
      fay[i] = *(const bf16x8*)(sAy + ro);
      fax[i] = *(const bf16x8*)(sAx + ro);
    }
#pragma unroll
    for (int j = 0; j < 4; j++) {
      int ro = (wn + j * 16 + rr) * 32 + q * 8;
      fbr[j] = *(const bf16x8*)(sBr + ro);
      fbg[j] = *(const bf16x8*)(sBg + ro);
    }
#pragma unroll
    for (int i = 0; i < 4; i++)
#pragma unroll
      for (int j = 0; j < 4; j++) {
        accR[i][j] = __builtin_amdgcn_mfma_f32_16x16x32_bf16(fay[i], fbr[j], accR[i][j], 0, 0, 0);
        accG[i][j] = __builtin_amdgcn_mfma_f32_16x16x32_bf16(fax[i], fbg[j], accG[i][j], 0, 0, 0);
      }
    __syncthreads();
  }
#pragma unroll
  for (int i = 0; i < 4; i++) {
#pragma unroll
    for (int j = 0; j < 4; j++) {
      int mbase = m0 + wm + i * 16 + q * 4;
      int n = n0 + wn + j * 16 + rr;
      float rbn = rb[n];
      float gbn = gb[n];
#pragma unroll
      for (int r = 0; r < 4; r++) {
        size_t idx = (size_t)(mbase + r) * 1024 + n;
        float refined = accR[i][j][r] + rbn;
        float gpre = accG[i][j][r] + gbn;
        float gate = 1.0f / (1.0f + __expf(-gpre));
        float xv = xin[idx];
        float o = gate * refined + (1.0f - gate) * xv;
        xout[idx] = o;
        xbfout[idx] = (__bf16)o;
      }
    }
  }
}

// ---------------- final logits GEMM: (4096x1024) @ (32000x1024)^T + bias ----------------
__global__ __launch_bounds__(256, 2) void k_gemm_logits(
    const __bf16* __restrict__ A, const __bf16* __restrict__ Bt,
    const float* __restrict__ bias, float* __restrict__ out) {
  __shared__ __align__(16) __bf16 sA[128 * 32];
  __shared__ __align__(16) __bf16 sB[128 * 32];
  int t = threadIdx.x;
  int n0 = blockIdx.x * 128;
  int m0 = blockIdx.y * 128;
  int wave = t >> 6, lane = t & 63;
  int q = lane >> 4, rr = lane & 15;
  int wm = (wave >> 1) * 64, wn = (wave & 1) * 64;
  int srow = t >> 2;
  int scol = (t & 3) * 8;
  unsigned ldsoff = (unsigned)wave * 1024;
  f32x4 zero = {0.f, 0.f, 0.f, 0.f};
  f32x4 acc[4][4];
#pragma unroll
  for (int i = 0; i < 4; i++)
#pragma unroll
    for (int j = 0; j < 4; j++) acc[i][j] = zero;

  for (int kk = 0; kk < 1024; kk += 32) {
#pragma unroll
    for (int c = 0; c < 2; c++) {
      size_t ga = (size_t)(m0 + c * 64 + srow) * 1024 + kk + scol;
      size_t gb = (size_t)(n0 + c * 64 + srow) * 1024 + kk + scol;
      unsigned lo = c * 4096 + ldsoff;
      async_cp16(A + ga, (char*)sA + lo);
      async_cp16(Bt + gb, (char*)sB + lo);
    }
    __syncthreads();
    bf16x8 fa[4], fb[4];
#pragma unroll
    for (int i = 0; i < 4; i++) fa[i] = *(const bf16x8*)(sA + (wm + i * 16 + rr) * 32 + q * 8);
#pragma unroll
    for (int j = 0; j < 4; j++) fb[j] = *(const bf16x8*)(sB + (wn + j * 16 + rr) * 32 + q * 8);
#pragma unroll
    for (int i = 0; i < 4; i++)
#pragma unroll
      for (int j = 0; j < 4; j++)
        acc[i][j] = __builtin_amdgcn_mfma_f32_16x16x32_bf16(fa[i], fb[j], acc[i][j], 0, 0, 0);
    __syncthreads();
  }
#pragma unroll
  for (int i = 0; i < 4; i++) {
#pragma unroll
    for (int j = 0; j < 4; j++) {
      int mbase = m0 + wm + i * 16 + q * 4;
      int n = n0 + wn + j * 16 + rr;
      float bn = bias[n];
#pragma unroll
      for (int r = 0; r < 4; r++) {
        out[(size_t)(mbase + r) * Vm + n] = acc[i][j][r] + bn;
      }
    }
  }
}

extern "C" void kernel_launch(void* const* d_in, const int* in_sizes, int n_in,
                              void* d_out, int out_size, void* d_ws, size_t ws_size,
                              hipStream_t stream) {
  const int* ids = (const int*)d_in[0];
  const float* emb = (const float*)d_in[1];
  const float* local_w = (const float*)d_in[2];
  const float* filt_w = (const float*)d_in[3];
  const float* mix_w = (const float*)d_in[4];
  const float* ln1_g = (const float*)d_in[5];
  const float* ln1_b = (const float*)d_in[6];
  const float* ref_W = (const float*)d_in[7];
  const float* ref_b = (const float*)d_in[8];
  const float* gate_W = (const float*)d_in[9];
  const float* gate_b = (const float*)d_in[10];
  const float* lnf_g = (const float*)d_in[11];
  const float* lnf_b = (const float*)d_in[12];
  const float* out_W = (const float*)d_in[13];
  const float* out_b = (const float*)d_in[14];
  float* logits = (float*)d_out;

  // Scratch that is dead before the final GEMM lives inside d_out (524 MB,
  // fully overwritten by k_gemm_logits at the end). ws only holds what the
  // final GEMM reads: Wt_bf (65.5 MB) + xf_bf (8.4 MB) => ~74 MB of ws used.
  char* ob = (char*)d_out;
  float* x0   = (float*)(ob + 0);
  float* x1   = (float*)(ob + 16777216);
  __bf16* xbf0 = (__bf16*)(ob + 33554432);
  __bf16* xbf1 = (__bf16*)(ob + 41943040);
  float* hbuf = (float*)(ob + 50331648);
  __bf16* ybf  = (__bf16*)(ob + 67108864);
  __bf16* rWbf = (__bf16*)(ob + 75497472);
  __bf16* gWbf = (__bf16*)(ob + 88080384);
  char* ws = (char*)d_ws;
  __bf16* Wtbf = (__bf16*)(ws + 0);
  __bf16* xfbf = (__bf16*)(ws + 65536000);

  k_cvt_bf16<<<6144, 256, 0, stream>>>(ref_W, rWbf, 1572864);
  k_cvt_bf16<<<6144, 256, 0, stream>>>(gate_W, gWbf, 1572864);
  k_transpose_cvt<<<dim3(1000, 32), 256, 0, stream>>>(out_W, Wtbf);
  k_embed<<<4096, 256, 0, stream>>>(ids, emb, x0, xbf0);

  float* xc = x0; float* xn = x1;
  __bf16* xbc = xbf0; __bf16* xbn = xbf1;
  for (int l = 0; l < NLm; l++) {
    k_ln_f32<<<4096, 256, 0, stream>>>(xc, ln1_g + l * 1024, ln1_b + l * 1024, hbuf);
    k_conv<<<dim3(8, 64, 2), 256, 0, stream>>>(
        hbuf, local_w + l * 3072,
        filt_w + (size_t)l * 131072, filt_w + (size_t)l * 131072 + 65536,
        mix_w + l * 1024, ybf);
    k_dual_gemm<<<dim3(8, 32), 256, 0, stream>>>(
        ybf, xbc, rWbf + (size_t)l * 1048576, gWbf + (size_t)l * 1048576,
        ref_b + l * 1024, gate_b + l * 1024, xc, xn, xbn);
    float* tf = xc; xc = xn; xn = tf;
    __bf16* tb = xbc; xbc = xbn; xbn = tb;
  }
  k_ln_bf16<<<4096, 256, 0, stream>>>(xc, lnf_g, lnf_b, xfbf);
  k_gemm_logits<<<dim3(250, 32), 256, 0, stream>>>(xfbf, Wtbf, out_b, logits);
}